// Round 5
// baseline (433.183 us; speedup 1.0000x reference)
//
#include <hip/hip_runtime.h>
#include <hip/hip_bf16.h>

// Problem constants
#define NND 50000      // nodes
#define NED 800000     // edges (without self-loops)
#define INC 10
#define HID 96
#define OUTC 48
#define NOUT (NND*OUTC)
#define NBLK 196       // ceil(NND/256)

typedef __hip_bfloat16 bf16;

// ---- workspace layout ----
// [0,16): flags.  Float region (offsets in floats from F):
#define XF_O   0L                 // 500000  (x: N x 10)
#define W1F_O  500000L            // 960   (W1 then b1 contiguous: 1056)
#define B1F_O  500960L            // 96
#define WMT_O  501056L            // 4608  TRANSPOSED: WMT[j][k] = W_mu[k][j]
#define BMF_O  505664L            // 48
#define WLT_O  505712L            // 4608  TRANSPOSED: WLT[j][k] = W_ls[k][j]
#define BLF_O  510320L            // 48
#define DIS_O  510368L            // 50000 (rsqrt(deg+1))
#define FLOATS_TOT 560368L
// bf16 h region: NND*96 ushorts right after floats.
// int region after h: cnt / start / cursor / bsum / boff / edges(int2)
#define CNT_IO   0L               // 50000
#define START_IO 50000L           // 50001 (+1 pad)
#define CUR_IO   100002L          // 50000
#define BS_IO    150002L          // 256
#define BOFF_IO  150258L          // 256 (pad to even)
#define EDGE_IO  150528L          // 800000 int2 {src, bitcast norm}; 8B-aligned

__device__ __forceinline__ float b2f(bf16 v) { return __bfloat162float(v); }
__device__ __forceinline__ float bfLo(unsigned int p) { return __uint_as_float(p << 16); }
__device__ __forceinline__ float bfHi(unsigned int p) { return __uint_as_float(p & 0xffff0000u); }

// K0: runtime dtype sniffer (deterministic every call)
__global__ __launch_bounds__(256) void k_sniff(const int* ei, const unsigned short* xs, int* flags) {
    __shared__ int s_oddnz, s_big;
    if (threadIdx.x == 0) { s_oddnz = 0; s_big = 0; }
    __syncthreads();
    int t = threadIdx.x;
    if (t < 128) {
        if (ei[2 * t + 1] != 0) atomicOr(&s_oddnz, 1);
    }
    for (int k = 0; k < 8; ++k) {
        unsigned short u = xs[t * 8 + k];
        float f = __uint_as_float(((unsigned int)u) << 16);
        if (!(fabsf(f) < 64.0f)) atomicOr(&s_big, 1);
    }
    __syncthreads();
    if (threadIdx.x == 0) {
        flags[0] = (s_oddnz == 0) ? 1 : 0;  // iw: 1 = int64
        flags[1] = s_big ? 1 : 0;           // ff: 1 = fp32
    }
}

// K1: fused convert-to-fp32 (+ transpose of the two head weights) + degree count
#define CVT_TOT 510368
#define DEG_THREADS 200000
__global__ __launch_bounds__(256) void k_prep(const void* x, const void* w1, const void* b1,
                                              const void* wm, const void* bm,
                                              const void* wl, const void* bl,
                                              const int* ei, const int* flags,
                                              float* F, int* cnt) {
    int idx = blockIdx.x * 256 + threadIdx.x;
    if (idx < CVT_TOT) {
        int ff = flags[1];
        const void* src; long off;
        if      (idx < 500000) { src = x;  off = idx; }
        else if (idx < 500960) { src = w1; off = idx - 500000; }
        else if (idx < 501056) { src = b1; off = idx - 500960; }
        else if (idx < 505664) { src = wm; off = idx - 501056; }
        else if (idx < 505712) { src = bm; off = idx - 505664; }
        else if (idx < 510320) { src = wl; off = idx - 505712; }
        else                   { src = bl; off = idx - 510320; }
        float v = ff ? ((const float*)src)[off] : b2f(((const bf16*)src)[off]);
        long dst = idx;
        if (idx >= 501056 && idx < 505664) {          // W_mu -> [j][k]
            long rel = idx - 501056;
            dst = WMT_O + (rel % OUTC) * (long)HID + rel / OUTC;
        } else if (idx >= 505712 && idx < 510320) {   // W_ls -> [j][k]
            long rel = idx - 505712;
            dst = WLT_O + (rel % OUTC) * (long)HID + rel / OUTC;
        }
        F[dst] = v;
    } else if (idx < CVT_TOT + DEG_THREADS) {
        int j = idx - CVT_TOT;
        if (flags[0]) {
            const int4* p = (const int4*)(ei + 2L * NED);
            int4 a = p[2 * j], b = p[2 * j + 1];
            atomicAdd(&cnt[a.x], 1); atomicAdd(&cnt[a.z], 1);
            atomicAdd(&cnt[b.x], 1); atomicAdd(&cnt[b.z], 1);
        } else {
            const int4* p = (const int4*)(ei + NED);
            int4 a = p[j];
            atomicAdd(&cnt[a.x], 1); atomicAdd(&cnt[a.y], 1);
            atomicAdd(&cnt[a.z], 1); atomicAdd(&cnt[a.w], 1);
        }
    }
}

// K2a: per-block sums of cnt (wave shuffle reduce)
__global__ __launch_bounds__(256) void k_bsum(const int* cnt, int* bsum) {
    int i = blockIdx.x * 256 + threadIdx.x;
    int v = (i < NND) ? cnt[i] : 0;
#pragma unroll
    for (int off = 32; off >= 1; off >>= 1) v += __shfl_down(v, off, 64);
    __shared__ int ws[4];
    int wid = threadIdx.x >> 6, lane = threadIdx.x & 63;
    if (lane == 0) ws[wid] = v;
    __syncthreads();
    if (threadIdx.x == 0) bsum[blockIdx.x] = ws[0] + ws[1] + ws[2] + ws[3];
}

// K2b: single small block scans the 196 block sums -> exclusive offsets
__global__ __launch_bounds__(256) void k_scan2(const int* bsum, int* boff) {
    __shared__ int lds[256];
    int tid = threadIdx.x;
    int v = (tid < NBLK) ? bsum[tid] : 0;
    lds[tid] = v;
    __syncthreads();
    int incl = v;
    for (int off = 1; off < 256; off <<= 1) {
        int t = (tid >= off) ? lds[tid - off] : 0;
        __syncthreads();
        incl += t; lds[tid] = incl;
        __syncthreads();
    }
    if (tid < NBLK) boff[tid] = incl - v;
}

// K2c: block-local exclusive scan + offset -> start/cursor; dis=rsqrt(deg+1)
__global__ __launch_bounds__(256) void k_fill(const int* cnt, const int* boff,
                                              int* start, int* cursor, float* F) {
    __shared__ int lds[256];
    int tid = threadIdx.x;
    int i = blockIdx.x * 256 + tid;
    int c = (i < NND) ? cnt[i] : 0;
    lds[tid] = c;
    __syncthreads();
    int incl = c;
    for (int off = 1; off < 256; off <<= 1) {
        int t = (tid >= off) ? lds[tid - off] : 0;
        __syncthreads();
        incl += t; lds[tid] = incl;
        __syncthreads();
    }
    int run = boff[blockIdx.x] + incl - c;
    if (i <= NND) start[i] = run;        // i==NND lands here -> total == NED
    if (i < NND) {
        cursor[i] = run;
        F[DIS_O + i] = rsqrtf((float)c + 1.0f);
    }
}

// K3: scatter edges into CSR order, 2 edges/thread (record = {src, norm})
__global__ __launch_bounds__(256) void k_scatter(const int* ei, const int* flags,
                                                 const float* F, int* cursor, int2* edges) {
    int j = blockIdx.x * 256 + threadIdx.x;
    if (j >= NED / 2) return;
    int iw = flags[0];
    int r0, c0, r1, c1;
    if (iw) {
        int4 rr = ((const int4*)ei)[j];
        int4 cc = ((const int4*)(ei + 2L * NED))[j];
        r0 = rr.x; r1 = rr.z; c0 = cc.x; c1 = cc.z;
    } else {
        int2 rr = ((const int2*)ei)[j];
        int2 cc = ((const int2*)(ei + NED))[j];
        r0 = rr.x; r1 = rr.y; c0 = cc.x; c1 = cc.y;
    }
    int p0 = atomicAdd(&cursor[c0], 1);
    edges[p0] = make_int2(r0, __float_as_int(F[DIS_O + r0] * F[DIS_O + c0]));
    int p1 = atomicAdd(&cursor[c1], 1);
    edges[p1] = make_int2(r1, __float_as_int(F[DIS_O + r1] * F[DIS_O + c1]));
}

// K4: fused layer1 — FOUR threads per node (quad in-wave): each takes every
// 4th edge, butterfly-combines the 10 partials, then emits 24 of 96 h feats.
__global__ __launch_bounds__(256) void k_layer1(const int* start, const int2* edges,
                                                const float* F, unsigned short* h) {
    __shared__ float w1s[1056];   // W1 (960) then b1 (96), contiguous in F
    for (int i = threadIdx.x; i < 1056; i += 256) w1s[i] = F[W1F_O + i];
    __syncthreads();
    int idx = blockIdx.x * 256 + threadIdx.x;
    if (idx >= NND * 4) return;
    int node = idx >> 2, sub = idx & 3;
    float ax[INC];
#pragma unroll
    for (int j = 0; j < INC; ++j) ax[j] = 0.0f;
    int s = start[node], t = start[node + 1];
    for (int k = s + sub; k < t; k += 4) {
        int2 rec = edges[k];
        float n = __int_as_float(rec.y);
        const float2* xr = (const float2*)(F + XF_O + (long)rec.x * INC);
#pragma unroll
        for (int j = 0; j < 5; ++j) {
            float2 v = xr[j];
            ax[2 * j]     = fmaf(n, v.x, ax[2 * j]);
            ax[2 * j + 1] = fmaf(n, v.y, ax[2 * j + 1]);
        }
    }
    if (sub == 0) {   // self-loop once
        float d = F[DIS_O + node]; float dd = d * d;
        const float2* xr = (const float2*)(F + XF_O + (long)node * INC);
#pragma unroll
        for (int j = 0; j < 5; ++j) {
            float2 v = xr[j];
            ax[2 * j]     = fmaf(dd, v.x, ax[2 * j]);
            ax[2 * j + 1] = fmaf(dd, v.y, ax[2 * j + 1]);
        }
    }
    // quad butterfly (quads are wave-aligned: masks 1,2 stay inside the quad)
#pragma unroll
    for (int j = 0; j < INC; ++j) {
        ax[j] += __shfl_xor(ax[j], 1, 64);
        ax[j] += __shfl_xor(ax[j], 2, 64);
    }
    // this thread emits features [sub*24, sub*24+24)
    int f0 = sub * 24;
    unsigned int* hrow = (unsigned int*)(h + (size_t)node * HID);
#pragma unroll
    for (int f = f0; f < f0 + 24; f += 2) {
        float a0 = w1s[960 + f], a1 = w1s[960 + f + 1];
#pragma unroll
        for (int kk = 0; kk < INC; ++kk) {
            a0 = fmaf(ax[kk], w1s[kk * HID + f], a0);
            a1 = fmaf(ax[kk], w1s[kk * HID + f + 1], a1);
        }
        a0 = fmaxf(a0, 0.0f); a1 = fmaxf(a1, 0.0f);
        unsigned int u0 = __bfloat16_as_ushort(__float2bfloat16(a0));
        unsigned int u1 = __bfloat16_as_ushort(__float2bfloat16(a1));
        hrow[f >> 1] = u0 | (u1 << 16);
    }
}

// K5: one wave per node — 8-edge-unrolled gather of bf16 h, self-loop,
// LDS round-trip, float4 transposed-weight dual GEMV + store.
__global__ __launch_bounds__(256) void k_gaggh_out(const int* start, const int2* edges,
                                                   const float* F, const unsigned short* h,
                                                   const int* flags, void* dout) {
    __shared__ float vbuf[4][HID];
    int wid = threadIdx.x >> 6;
    int lane = threadIdx.x & 63;
    int node = blockIdx.x * 4 + wid;
    const unsigned int* hb = (const unsigned int*)h;

    if (lane < 48) {
        int s = start[node], t = start[node + 1];
        float a0 = 0.0f, a1 = 0.0f;
        int k = s;
        for (; k + 7 < t; k += 8) {
            int2 e0 = edges[k],     e1 = edges[k + 1], e2 = edges[k + 2], e3 = edges[k + 3];
            int2 e4 = edges[k + 4], e5 = edges[k + 5], e6 = edges[k + 6], e7 = edges[k + 7];
            unsigned int p0 = hb[(size_t)e0.x * 48 + lane];
            unsigned int p1 = hb[(size_t)e1.x * 48 + lane];
            unsigned int p2 = hb[(size_t)e2.x * 48 + lane];
            unsigned int p3 = hb[(size_t)e3.x * 48 + lane];
            unsigned int p4 = hb[(size_t)e4.x * 48 + lane];
            unsigned int p5 = hb[(size_t)e5.x * 48 + lane];
            unsigned int p6 = hb[(size_t)e6.x * 48 + lane];
            unsigned int p7 = hb[(size_t)e7.x * 48 + lane];
            a0 = fmaf(__int_as_float(e0.y), bfLo(p0), a0); a1 = fmaf(__int_as_float(e0.y), bfHi(p0), a1);
            a0 = fmaf(__int_as_float(e1.y), bfLo(p1), a0); a1 = fmaf(__int_as_float(e1.y), bfHi(p1), a1);
            a0 = fmaf(__int_as_float(e2.y), bfLo(p2), a0); a1 = fmaf(__int_as_float(e2.y), bfHi(p2), a1);
            a0 = fmaf(__int_as_float(e3.y), bfLo(p3), a0); a1 = fmaf(__int_as_float(e3.y), bfHi(p3), a1);
            a0 = fmaf(__int_as_float(e4.y), bfLo(p4), a0); a1 = fmaf(__int_as_float(e4.y), bfHi(p4), a1);
            a0 = fmaf(__int_as_float(e5.y), bfLo(p5), a0); a1 = fmaf(__int_as_float(e5.y), bfHi(p5), a1);
            a0 = fmaf(__int_as_float(e6.y), bfLo(p6), a0); a1 = fmaf(__int_as_float(e6.y), bfHi(p6), a1);
            a0 = fmaf(__int_as_float(e7.y), bfLo(p7), a0); a1 = fmaf(__int_as_float(e7.y), bfHi(p7), a1);
        }
        for (; k + 1 < t; k += 2) {
            int2 e0 = edges[k], e1 = edges[k + 1];
            unsigned int p0 = hb[(size_t)e0.x * 48 + lane];
            unsigned int p1 = hb[(size_t)e1.x * 48 + lane];
            a0 = fmaf(__int_as_float(e0.y), bfLo(p0), a0); a1 = fmaf(__int_as_float(e0.y), bfHi(p0), a1);
            a0 = fmaf(__int_as_float(e1.y), bfLo(p1), a0); a1 = fmaf(__int_as_float(e1.y), bfHi(p1), a1);
        }
        if (k < t) {
            int2 e0 = edges[k];
            unsigned int p0 = hb[(size_t)e0.x * 48 + lane];
            a0 = fmaf(__int_as_float(e0.y), bfLo(p0), a0); a1 = fmaf(__int_as_float(e0.y), bfHi(p0), a1);
        }
        float d = F[DIS_O + node]; float dd = d * d;
        unsigned int ps = hb[(size_t)node * 48 + lane];
        a0 = fmaf(dd, bfLo(ps), a0); a1 = fmaf(dd, bfHi(ps), a1);
        ((float2*)vbuf[wid])[lane] = make_float2(a0, a1);
    }
    __syncthreads();

    if (lane < OUTC) {
        const float4* wm4 = (const float4*)(F + WMT_O + (long)lane * HID);
        const float4* wl4 = (const float4*)(F + WLT_O + (long)lane * HID);
        const float4* vb4 = (const float4*)(vbuf[wid]);
        float am0 = F[BMF_O + lane], am1 = 0.0f;
        float al0 = F[BLF_O + lane], al1 = 0.0f;
#pragma unroll
        for (int g = 0; g < HID / 4; g += 2) {
            float4 v0 = vb4[g], v1 = vb4[g + 1];
            float4 m0 = wm4[g], m1 = wm4[g + 1];
            float4 l0 = wl4[g], l1 = wl4[g + 1];
            am0 = fmaf(v0.x, m0.x, am0); am0 = fmaf(v0.y, m0.y, am0);
            am0 = fmaf(v0.z, m0.z, am0); am0 = fmaf(v0.w, m0.w, am0);
            am1 = fmaf(v1.x, m1.x, am1); am1 = fmaf(v1.y, m1.y, am1);
            am1 = fmaf(v1.z, m1.z, am1); am1 = fmaf(v1.w, m1.w, am1);
            al0 = fmaf(v0.x, l0.x, al0); al0 = fmaf(v0.y, l0.y, al0);
            al0 = fmaf(v0.z, l0.z, al0); al0 = fmaf(v0.w, l0.w, al0);
            al1 = fmaf(v1.x, l1.x, al1); al1 = fmaf(v1.y, l1.y, al1);
            al1 = fmaf(v1.z, l1.z, al1); al1 = fmaf(v1.w, l1.w, al1);
        }
        float am = am0 + am1, al = al0 + al1;
        long oi = (long)node * OUTC + lane;
        if (flags[1]) {
            float* o = (float*)dout;
            o[oi] = am; o[NOUT + oi] = al;
        } else {
            bf16* o = (bf16*)dout;
            o[oi] = __float2bfloat16(am);
            o[NOUT + oi] = __float2bfloat16(al);
        }
    }
}

extern "C" void kernel_launch(void* const* d_in, const int* in_sizes, int n_in,
                              void* d_out, int out_size, void* d_ws, size_t ws_size,
                              hipStream_t stream) {
    const int* ei = (const int*)d_in[1];
    int* flags = (int*)d_ws;
    float* F = (float*)((char*)d_ws + 16);
    unsigned short* h = (unsigned short*)((char*)d_ws + 16 + FLOATS_TOT * 4);
    int* intBase = (int*)((char*)h + (size_t)NND * HID * 2);
    int* cnt    = intBase + CNT_IO;
    int* start  = intBase + START_IO;
    int* cursor = intBase + CUR_IO;
    int* bsum   = intBase + BS_IO;
    int* boff   = intBase + BOFF_IO;
    int2* edges = (int2*)(intBase + EDGE_IO);

    hipMemsetAsync(cnt, 0, NND * 4, stream);

    k_sniff<<<1, 256, 0, stream>>>(ei, (const unsigned short*)d_in[0], flags);
    k_prep<<<(CVT_TOT + DEG_THREADS + 255) / 256, 256, 0, stream>>>(
        d_in[0], d_in[2], d_in[3], d_in[4], d_in[5], d_in[6], d_in[7], ei, flags, F, cnt);
    k_bsum<<<NBLK, 256, 0, stream>>>(cnt, bsum);
    k_scan2<<<1, 256, 0, stream>>>(bsum, boff);
    k_fill<<<NBLK, 256, 0, stream>>>(cnt, boff, start, cursor, F);
    k_scatter<<<(NED / 2 + 255) / 256, 256, 0, stream>>>(ei, flags, F, cursor, edges);
    k_layer1<<<(NND * 4 + 255) / 256, 256, 0, stream>>>(start, edges, F, h);
    k_gaggh_out<<<NND / 4, 256, 0, stream>>>(start, edges, F, h, flags, d_out);
}

// Round 6
// 234.183 us; speedup vs baseline: 1.8498x; 1.8498x over previous
//
#include <hip/hip_runtime.h>
#include <hip/hip_bf16.h>

// Problem constants
#define NND 50000      // nodes
#define NED 800000     // edges (without self-loops)
#define INC 10
#define HID 96
#define OUTC 48
#define NOUT (NND*OUTC)
#define NBLK 196       // ceil(NND/256)
#define MTILES 3125    // 50000 / 16

typedef __hip_bfloat16 bf16;
typedef __attribute__((ext_vector_type(8))) short short8;
typedef __attribute__((ext_vector_type(4))) float f32x4;

// ---- workspace layout ----
// [0,16): flags.  Float region (offsets in floats from F):
#define XF_O   0L                 // 500000  (x: N x 10)
#define W1F_O  500000L            // 960   (W1 then b1 contiguous: 1056)
#define B1F_O  500960L            // 96
#define WMF_O  501056L            // 4608  (plain fp32 copy, unused by heads)
#define BMF_O  505664L            // 48
#define WLF_O  505712L            // 4608
#define BLF_O  510320L            // 48
#define DIS_O  510368L            // 50000 (rsqrt(deg+1))
#define FLOATS_TOT 560368L
// after floats: h   [NND*96] ushort (bf16)
//               wct [96*96]  ushort (bf16)  WcatT[n][k]; n<48 = W_mu col, n>=48 = W_ls col
//               v   [NND*96] ushort (bf16)  aggregated hidden
// int region after v: cnt / start / cursor / bsum / boff / edges(int2)
#define CNT_IO   0L               // 50000
#define START_IO 50000L           // 50001 (+1 pad)
#define CUR_IO   100002L          // 50000
#define BS_IO    150002L          // 256
#define BOFF_IO  150258L          // 256 (pad to even)
#define EDGE_IO  150528L          // 800000 int2 {src, bitcast norm}; 8B-aligned

__device__ __forceinline__ float b2f(bf16 v) { return __bfloat162float(v); }
__device__ __forceinline__ float bfLo(unsigned int p) { return __uint_as_float(p << 16); }
__device__ __forceinline__ float bfHi(unsigned int p) { return __uint_as_float(p & 0xffff0000u); }
__device__ __forceinline__ unsigned short f2bu(float v) {
    return __bfloat16_as_ushort(__float2bfloat16(v));
}

// K0: runtime dtype sniffer (deterministic every call)
__global__ __launch_bounds__(256) void k_sniff(const int* ei, const unsigned short* xs, int* flags) {
    __shared__ int s_oddnz, s_big;
    if (threadIdx.x == 0) { s_oddnz = 0; s_big = 0; }
    __syncthreads();
    int t = threadIdx.x;
    if (t < 128) {
        if (ei[2 * t + 1] != 0) atomicOr(&s_oddnz, 1);
    }
    for (int k = 0; k < 8; ++k) {
        unsigned short u = xs[t * 8 + k];
        float f = __uint_as_float(((unsigned int)u) << 16);
        if (!(fabsf(f) < 64.0f)) atomicOr(&s_big, 1);
    }
    __syncthreads();
    if (threadIdx.x == 0) {
        flags[0] = (s_oddnz == 0) ? 1 : 0;  // iw: 1 = int64
        flags[1] = s_big ? 1 : 0;           // ff: 1 = fp32
    }
}

// K1: fused convert-to-fp32 + bf16 transposed head-weight build + degree count
#define CVT_TOT 510368
#define DEG_THREADS 200000
__global__ __launch_bounds__(256) void k_prep(const void* x, const void* w1, const void* b1,
                                              const void* wm, const void* bm,
                                              const void* wl, const void* bl,
                                              const int* ei, const int* flags,
                                              float* F, unsigned short* wct, int* cnt) {
    int idx = blockIdx.x * 256 + threadIdx.x;
    if (idx < CVT_TOT) {
        int ff = flags[1];
        const void* src; long off;
        if      (idx < 500000) { src = x;  off = idx; }
        else if (idx < 500960) { src = w1; off = idx - 500000; }
        else if (idx < 501056) { src = b1; off = idx - 500960; }
        else if (idx < 505664) { src = wm; off = idx - 501056; }
        else if (idx < 505712) { src = bm; off = idx - 505664; }
        else if (idx < 510320) { src = wl; off = idx - 505712; }
        else                   { src = bl; off = idx - 510320; }
        float v = ff ? ((const float*)src)[off] : b2f(((const bf16*)src)[off]);
        F[idx] = v;
        if (idx >= 501056 && idx < 505664) {          // W_mu[k][j] -> wct[j][k]
            long rel = idx - 501056;
            wct[(rel % OUTC) * (long)HID + rel / OUTC] = f2bu(v);
        } else if (idx >= 505712 && idx < 510320) {   // W_ls[k][j] -> wct[48+j][k]
            long rel = idx - 505712;
            wct[(OUTC + rel % OUTC) * (long)HID + rel / OUTC] = f2bu(v);
        }
    } else if (idx < CVT_TOT + DEG_THREADS) {
        int j = idx - CVT_TOT;
        if (flags[0]) {
            const int4* p = (const int4*)(ei + 2L * NED);
            int4 a = p[2 * j], b = p[2 * j + 1];
            atomicAdd(&cnt[a.x], 1); atomicAdd(&cnt[a.z], 1);
            atomicAdd(&cnt[b.x], 1); atomicAdd(&cnt[b.z], 1);
        } else {
            const int4* p = (const int4*)(ei + NED);
            int4 a = p[j];
            atomicAdd(&cnt[a.x], 1); atomicAdd(&cnt[a.y], 1);
            atomicAdd(&cnt[a.z], 1); atomicAdd(&cnt[a.w], 1);
        }
    }
}

// K2a: per-block sums of cnt (wave shuffle reduce)
__global__ __launch_bounds__(256) void k_bsum(const int* cnt, int* bsum) {
    int i = blockIdx.x * 256 + threadIdx.x;
    int v = (i < NND) ? cnt[i] : 0;
#pragma unroll
    for (int off = 32; off >= 1; off >>= 1) v += __shfl_down(v, off, 64);
    __shared__ int ws[4];
    int wid = threadIdx.x >> 6, lane = threadIdx.x & 63;
    if (lane == 0) ws[wid] = v;
    __syncthreads();
    if (threadIdx.x == 0) bsum[blockIdx.x] = ws[0] + ws[1] + ws[2] + ws[3];
}

// K2b: single small block scans the 196 block sums -> exclusive offsets
__global__ __launch_bounds__(256) void k_scan2(const int* bsum, int* boff) {
    __shared__ int lds[256];
    int tid = threadIdx.x;
    int v = (tid < NBLK) ? bsum[tid] : 0;
    lds[tid] = v;
    __syncthreads();
    int incl = v;
    for (int off = 1; off < 256; off <<= 1) {
        int t = (tid >= off) ? lds[tid - off] : 0;
        __syncthreads();
        incl += t; lds[tid] = incl;
        __syncthreads();
    }
    if (tid < NBLK) boff[tid] = incl - v;
}

// K2c: block-local exclusive scan + offset -> start/cursor; dis=rsqrt(deg+1)
__global__ __launch_bounds__(256) void k_fill(const int* cnt, const int* boff,
                                              int* start, int* cursor, float* F) {
    __shared__ int lds[256];
    int tid = threadIdx.x;
    int i = blockIdx.x * 256 + tid;
    int c = (i < NND) ? cnt[i] : 0;
    lds[tid] = c;
    __syncthreads();
    int incl = c;
    for (int off = 1; off < 256; off <<= 1) {
        int t = (tid >= off) ? lds[tid - off] : 0;
        __syncthreads();
        incl += t; lds[tid] = incl;
        __syncthreads();
    }
    int run = boff[blockIdx.x] + incl - c;
    if (i <= NND) start[i] = run;        // i==NND lands here -> total == NED
    if (i < NND) {
        cursor[i] = run;
        F[DIS_O + i] = rsqrtf((float)c + 1.0f);
    }
}

// K3: scatter edges into CSR order, 2 edges/thread (record = {src, norm})
__global__ __launch_bounds__(256) void k_scatter(const int* ei, const int* flags,
                                                 const float* F, int* cursor, int2* edges) {
    int j = blockIdx.x * 256 + threadIdx.x;
    if (j >= NED / 2) return;
    int iw = flags[0];
    int r0, c0, r1, c1;
    if (iw) {
        int4 rr = ((const int4*)ei)[j];
        int4 cc = ((const int4*)(ei + 2L * NED))[j];
        r0 = rr.x; r1 = rr.z; c0 = cc.x; c1 = cc.z;
    } else {
        int2 rr = ((const int2*)ei)[j];
        int2 cc = ((const int2*)(ei + NED))[j];
        r0 = rr.x; r1 = rr.y; c0 = cc.x; c1 = cc.y;
    }
    int p0 = atomicAdd(&cursor[c0], 1);
    edges[p0] = make_int2(r0, __float_as_int(F[DIS_O + r0] * F[DIS_O + c0]));
    int p1 = atomicAdd(&cursor[c1], 1);
    edges[p1] = make_int2(r1, __float_as_int(F[DIS_O + r1] * F[DIS_O + c1]));
}

// K4: fused layer1 — FOUR threads per node (quad in-wave): each takes every
// 4th edge, butterfly-combines the 10 partials, then emits 24 of 96 h feats.
__global__ __launch_bounds__(256) void k_layer1(const int* start, const int2* edges,
                                                const float* F, unsigned short* h) {
    __shared__ float w1s[1056];   // W1 (960) then b1 (96), contiguous in F
    for (int i = threadIdx.x; i < 1056; i += 256) w1s[i] = F[W1F_O + i];
    __syncthreads();
    int idx = blockIdx.x * 256 + threadIdx.x;
    if (idx >= NND * 4) return;
    int node = idx >> 2, sub = idx & 3;
    float ax[INC];
#pragma unroll
    for (int j = 0; j < INC; ++j) ax[j] = 0.0f;
    int s = start[node], t = start[node + 1];
    for (int k = s + sub; k < t; k += 4) {
        int2 rec = edges[k];
        float n = __int_as_float(rec.y);
        const float2* xr = (const float2*)(F + XF_O + (long)rec.x * INC);
#pragma unroll
        for (int j = 0; j < 5; ++j) {
            float2 v = xr[j];
            ax[2 * j]     = fmaf(n, v.x, ax[2 * j]);
            ax[2 * j + 1] = fmaf(n, v.y, ax[2 * j + 1]);
        }
    }
    if (sub == 0) {   // self-loop once
        float d = F[DIS_O + node]; float dd = d * d;
        const float2* xr = (const float2*)(F + XF_O + (long)node * INC);
#pragma unroll
        for (int j = 0; j < 5; ++j) {
            float2 v = xr[j];
            ax[2 * j]     = fmaf(dd, v.x, ax[2 * j]);
            ax[2 * j + 1] = fmaf(dd, v.y, ax[2 * j + 1]);
        }
    }
    // quad butterfly (quads are wave-aligned: masks 1,2 stay inside the quad)
#pragma unroll
    for (int j = 0; j < INC; ++j) {
        ax[j] += __shfl_xor(ax[j], 1, 64);
        ax[j] += __shfl_xor(ax[j], 2, 64);
    }
    // this thread emits features [sub*24, sub*24+24)
    int f0 = sub * 24;
    unsigned int* hrow = (unsigned int*)(h + (size_t)node * HID);
#pragma unroll
    for (int f = f0; f < f0 + 24; f += 2) {
        float a0 = w1s[960 + f], a1 = w1s[960 + f + 1];
#pragma unroll
        for (int kk = 0; kk < INC; ++kk) {
            a0 = fmaf(ax[kk], w1s[kk * HID + f], a0);
            a1 = fmaf(ax[kk], w1s[kk * HID + f + 1], a1);
        }
        a0 = fmaxf(a0, 0.0f); a1 = fmaxf(a1, 0.0f);
        unsigned int u0 = f2bu(a0), u1 = f2bu(a1);
        hrow[f >> 1] = u0 | (u1 << 16);
    }
}

// K5: pure gather-aggregate — one wave per node, lanes 0..47 hold feature
// pairs (2L,2L+1), 8-edge unroll, self-loop, write v as packed bf16.
// No LDS, no barrier, no weight traffic.
__global__ __launch_bounds__(256) void k_gaggh(const int* start, const int2* edges,
                                               const float* F, const unsigned short* h,
                                               unsigned int* v) {
    int wid = threadIdx.x >> 6;
    int lane = threadIdx.x & 63;
    int node = blockIdx.x * 4 + wid;
    if (lane >= 48) return;
    const unsigned int* hb = (const unsigned int*)h;

    int s = start[node], t = start[node + 1];
    float a0 = 0.0f, a1 = 0.0f;
    int k = s;
    for (; k + 7 < t; k += 8) {
        int2 e0 = edges[k],     e1 = edges[k + 1], e2 = edges[k + 2], e3 = edges[k + 3];
        int2 e4 = edges[k + 4], e5 = edges[k + 5], e6 = edges[k + 6], e7 = edges[k + 7];
        unsigned int p0 = hb[(size_t)e0.x * 48 + lane];
        unsigned int p1 = hb[(size_t)e1.x * 48 + lane];
        unsigned int p2 = hb[(size_t)e2.x * 48 + lane];
        unsigned int p3 = hb[(size_t)e3.x * 48 + lane];
        unsigned int p4 = hb[(size_t)e4.x * 48 + lane];
        unsigned int p5 = hb[(size_t)e5.x * 48 + lane];
        unsigned int p6 = hb[(size_t)e6.x * 48 + lane];
        unsigned int p7 = hb[(size_t)e7.x * 48 + lane];
        a0 = fmaf(__int_as_float(e0.y), bfLo(p0), a0); a1 = fmaf(__int_as_float(e0.y), bfHi(p0), a1);
        a0 = fmaf(__int_as_float(e1.y), bfLo(p1), a0); a1 = fmaf(__int_as_float(e1.y), bfHi(p1), a1);
        a0 = fmaf(__int_as_float(e2.y), bfLo(p2), a0); a1 = fmaf(__int_as_float(e2.y), bfHi(p2), a1);
        a0 = fmaf(__int_as_float(e3.y), bfLo(p3), a0); a1 = fmaf(__int_as_float(e3.y), bfHi(p3), a1);
        a0 = fmaf(__int_as_float(e4.y), bfLo(p4), a0); a1 = fmaf(__int_as_float(e4.y), bfHi(p4), a1);
        a0 = fmaf(__int_as_float(e5.y), bfLo(p5), a0); a1 = fmaf(__int_as_float(e5.y), bfHi(p5), a1);
        a0 = fmaf(__int_as_float(e6.y), bfLo(p6), a0); a1 = fmaf(__int_as_float(e6.y), bfHi(p6), a1);
        a0 = fmaf(__int_as_float(e7.y), bfLo(p7), a0); a1 = fmaf(__int_as_float(e7.y), bfHi(p7), a1);
    }
    for (; k + 1 < t; k += 2) {
        int2 e0 = edges[k], e1 = edges[k + 1];
        unsigned int p0 = hb[(size_t)e0.x * 48 + lane];
        unsigned int p1 = hb[(size_t)e1.x * 48 + lane];
        a0 = fmaf(__int_as_float(e0.y), bfLo(p0), a0); a1 = fmaf(__int_as_float(e0.y), bfHi(p0), a1);
        a0 = fmaf(__int_as_float(e1.y), bfLo(p1), a0); a1 = fmaf(__int_as_float(e1.y), bfHi(p1), a1);
    }
    if (k < t) {
        int2 e0 = edges[k];
        unsigned int p0 = hb[(size_t)e0.x * 48 + lane];
        a0 = fmaf(__int_as_float(e0.y), bfLo(p0), a0); a1 = fmaf(__int_as_float(e0.y), bfHi(p0), a1);
    }
    float d = F[DIS_O + node]; float dd = d * d;
    unsigned int ps = hb[(size_t)node * 48 + lane];
    a0 = fmaf(dd, bfLo(ps), a0); a1 = fmaf(dd, bfHi(ps), a1);
    v[(size_t)node * 48 + lane] = (unsigned int)f2bu(a0) | ((unsigned int)f2bu(a1) << 16);
}

// K6: MFMA head GEMM — v[50000,96]bf16 @ WcatT^T (= [96k,96n]) + bias -> d_out.
// One wave per 16-row M-tile, all 6 N-tiles, K=96 (3 MFMA each).
// Layouts (verified, §3): A: m=lane&15, k=quad*8+j; B: n=lane&15, k=quad*8+j;
// C/D: col(n)=lane&15, row(m)=quad*4+reg.
__global__ __launch_bounds__(256) void k_heads(const unsigned short* v, const unsigned short* wct,
                                               const float* F, const int* flags, void* dout) {
    int wid = threadIdx.x >> 6;
    int lane = threadIdx.x & 63;
    int mtile = blockIdx.x * 4 + wid;
    if (mtile >= MTILES) return;
    int l16 = lane & 15, quad = lane >> 4;

    const unsigned short* vb = v + ((size_t)mtile * 16 + l16) * HID + quad * 8;
    short8 afr0 = *(const short8*)(vb);
    short8 afr1 = *(const short8*)(vb + 32);
    short8 afr2 = *(const short8*)(vb + 64);

    int ff = flags[1];
#pragma unroll
    for (int nt = 0; nt < 6; ++nt) {
        const unsigned short* wb = wct + ((size_t)nt * 16 + l16) * HID + quad * 8;
        short8 b0 = *(const short8*)(wb);
        short8 b1 = *(const short8*)(wb + 32);
        short8 b2 = *(const short8*)(wb + 64);
        f32x4 acc = {0.0f, 0.0f, 0.0f, 0.0f};
        acc = __builtin_amdgcn_mfma_f32_16x16x32_bf16(afr0, b0, acc, 0, 0, 0);
        acc = __builtin_amdgcn_mfma_f32_16x16x32_bf16(afr1, b1, acc, 0, 0, 0);
        acc = __builtin_amdgcn_mfma_f32_16x16x32_bf16(afr2, b2, acc, 0, 0, 0);
        int n = nt * 16 + l16;                 // 0..95: <48 mu, >=48 logstd
        float bias = (n < OUTC) ? F[BMF_O + n] : F[BLF_O + n - OUTC];
        long obase = (n < OUTC) ? ((long)n) : (NOUT + (long)(n - OUTC));
#pragma unroll
        for (int r = 0; r < 4; ++r) {
            int m = mtile * 16 + quad * 4 + r;
            float val = acc[r] + bias;
            long oi = (long)m * OUTC + obase;
            if (ff) ((float*)dout)[oi] = val;
            else    ((bf16*)dout)[oi] = __float2bfloat16(val);
        }
    }
}

extern "C" void kernel_launch(void* const* d_in, const int* in_sizes, int n_in,
                              void* d_out, int out_size, void* d_ws, size_t ws_size,
                              hipStream_t stream) {
    const int* ei = (const int*)d_in[1];
    int* flags = (int*)d_ws;
    float* F = (float*)((char*)d_ws + 16);
    unsigned short* h   = (unsigned short*)((char*)d_ws + 16 + FLOATS_TOT * 4);
    unsigned short* wct = h + (size_t)NND * HID;
    unsigned short* vv  = wct + (size_t)HID * HID;
    int* intBase = (int*)(vv + (size_t)NND * HID);
    int* cnt    = intBase + CNT_IO;
    int* start  = intBase + START_IO;
    int* cursor = intBase + CUR_IO;
    int* bsum   = intBase + BS_IO;
    int* boff   = intBase + BOFF_IO;
    int2* edges = (int2*)(intBase + EDGE_IO);

    hipMemsetAsync(cnt, 0, NND * 4, stream);

    k_sniff<<<1, 256, 0, stream>>>(ei, (const unsigned short*)d_in[0], flags);
    k_prep<<<(CVT_TOT + DEG_THREADS + 255) / 256, 256, 0, stream>>>(
        d_in[0], d_in[2], d_in[3], d_in[4], d_in[5], d_in[6], d_in[7], ei, flags, F, wct, cnt);
    k_bsum<<<NBLK, 256, 0, stream>>>(cnt, bsum);
    k_scan2<<<1, 256, 0, stream>>>(bsum, boff);
    k_fill<<<NBLK, 256, 0, stream>>>(cnt, boff, start, cursor, F);
    k_scatter<<<(NED / 2 + 255) / 256, 256, 0, stream>>>(ei, flags, F, cursor, edges);
    k_layer1<<<(NND * 4 + 255) / 256, 256, 0, stream>>>(start, edges, F, h);
    k_gaggh<<<NND / 4, 256, 0, stream>>>(start, edges, F, h, (unsigned int*)vv);
    k_heads<<<(MTILES + 3) / 4, 256, 0, stream>>>(vv, wct, F, flags, d_out);
}